// Round 3
// baseline (1031.906 us; speedup 1.0000x reference)
//
#include <hip/hip_runtime.h>
#include <hip/hip_bf16.h>
#include <math.h>

// One thread per edge: analytic force, dual scatter via NATIVE fp32 atomics.
// unsafeAtomicAdd -> global_atomic_add_f32 (no-return, RMW at TCC/L2),
// avoiding the CAS loop that plain atomicAdd(float*) lowers to.
__global__ void __launch_bounds__(256)
edge_force_scatter_native(const float* __restrict__ disp,
                          const float* __restrict__ a,
                          const float* __restrict__ b,
                          const int* __restrict__ src,
                          const int* __restrict__ dst,
                          float* __restrict__ out,
                          int E) {
    int e = blockIdx.x * blockDim.x + threadIdx.x;
    if (e >= E) return;

    float dx = disp[3 * e + 0];
    float dy = disp[3 * e + 1];
    float dz = disp[3 * e + 2];
    float r2 = dx * dx + dy * dy + dz * dz;
    // force = -dE/ddisp = -2*disp*(a - b*exp(-r2))
    float coef = -2.0f * (a[e] - b[e] * __expf(-r2));
    float fx = coef * dx, fy = coef * dy, fz = coef * dz;

    int s = 3 * src[e];
    int d = 3 * dst[e];

    unsafeAtomicAdd(&out[s + 0], fx);
    unsafeAtomicAdd(&out[s + 1], fy);
    unsafeAtomicAdd(&out[s + 2], fz);
    unsafeAtomicAdd(&out[d + 0], -fx);
    unsafeAtomicAdd(&out[d + 1], -fy);
    unsafeAtomicAdd(&out[d + 2], -fz);
}

extern "C" void kernel_launch(void* const* d_in, const int* in_sizes, int n_in,
                              void* d_out, int out_size, void* d_ws, size_t ws_size,
                              hipStream_t stream) {
    const float* disp = (const float*)d_in[0];   // [E,3]
    const float* a    = (const float*)d_in[1];   // [E]
    const float* b    = (const float*)d_in[2];   // [E]
    const int*   ei   = (const int*)d_in[3];     // [2,E]

    int E = in_sizes[1];
    float* out = (float*)d_out;

    // Harness poisons d_out with 0xAA before every launch; zero it.
    hipMemsetAsync(d_out, 0, (size_t)out_size * sizeof(float), stream);

    int block = 256;
    int grid = (E + block - 1) / block;
    edge_force_scatter_native<<<grid, block, 0, stream>>>(
        disp, a, b, ei, ei + E, out, E);
}

// Round 4
// 327.379 us; speedup vs baseline: 3.1520x; 3.1520x over previous
//
#include <hip/hip_runtime.h>
#include <hip/hip_bf16.h>
#include <math.h>

// ---------------- tunables ----------------
constexpr int TPB          = 256;     // threads per block
constexpr int EPB          = 12800;   // edges per phase-1 block
constexpr int NODES_PER_B  = 256;     // nodes per bucket  (bin = node >> 8)
constexpr int C_SLOT       = 88;      // record slots per (bucket, block) group
constexpr int MAX_NB       = 1024;    // max buckets supported by LDS cursors
constexpr int MAX_BLOCKS   = 512;     // max phase-1 blocks (counts cached in LDS)
constexpr int OCAP         = 2000000; // overflow list capacity (records)

// Record: 16 B = { u32 node, f32 fx, f32 fy, f32 fz }  (sign pre-applied)

// ---------------- phase 1: force + bucket scatter ----------------
__global__ void __launch_bounds__(TPB)
p1_force_bucket(const float* __restrict__ disp,
                const float* __restrict__ a,
                const float* __restrict__ b,
                const int* __restrict__ src,
                const int* __restrict__ dst,
                uint4* __restrict__ records,
                int* __restrict__ counts,     // [NB][nblocks]
                uint4* __restrict__ ovf,
                int* __restrict__ ovf_cnt,
                int E, int NB, int nblocks) {
    __shared__ int cursor[MAX_NB];
    int t = threadIdx.x;
    for (int i = t; i < NB; i += TPB) cursor[i] = 0;
    __syncthreads();

    int blk = blockIdx.x;
    int base_e = blk * EPB;

    for (int k = 0; k < EPB; k += TPB) {
        int e = base_e + k + t;
        if (e < E) {
            float dx = disp[3 * e + 0];
            float dy = disp[3 * e + 1];
            float dz = disp[3 * e + 2];
            float r2 = dx * dx + dy * dy + dz * dz;
            // force = -dE/ddisp = -2*disp*(a - b*exp(-r2))
            float coef = -2.0f * (a[e] - b[e] * __expf(-r2));
            float fx = coef * dx, fy = coef * dy, fz = coef * dz;

            int nodes[2] = { src[e], dst[e] };
            float sgn[2] = { 1.0f, -1.0f };
#pragma unroll
            for (int j = 0; j < 2; ++j) {
                int node = nodes[j];
                int bin = node >> 8;
                uint4 rec;
                rec.x = (unsigned)node;
                rec.y = __float_as_uint(sgn[j] * fx);
                rec.z = __float_as_uint(sgn[j] * fy);
                rec.w = __float_as_uint(sgn[j] * fz);
                int r = atomicAdd(&cursor[bin], 1);          // LDS, native
                if (r < C_SLOT) {
                    records[((size_t)bin * nblocks + blk) * C_SLOT + r] = rec;
                } else {
                    int o = atomicAdd(ovf_cnt, 1);           // rare
                    if (o < OCAP) ovf[o] = rec;
                }
            }
        }
    }
    __syncthreads();
    for (int i = t; i < NB; i += TPB)
        counts[(size_t)i * nblocks + blk] = min(cursor[i], C_SLOT);
}

// ---------------- phase 2: per-bucket LDS reduce ----------------
__global__ void __launch_bounds__(TPB)
p2_bucket_reduce(const uint4* __restrict__ records,
                 const int* __restrict__ counts,
                 float* __restrict__ out,
                 int nblocks, int out_size) {
    __shared__ float accum[NODES_PER_B * 3];
    __shared__ int cnt[MAX_BLOCKS];
    int t = threadIdx.x;
    int bucket = blockIdx.x;

    for (int i = t; i < NODES_PER_B * 3; i += TPB) accum[i] = 0.0f;
    for (int i = t; i < nblocks; i += TPB)
        cnt[i] = counts[(size_t)bucket * nblocks + i];
    __syncthreads();

    const uint4* rbase = records + (size_t)bucket * nblocks * C_SLOT;
    int slots = nblocks * C_SLOT;
    for (int s = t; s < slots; s += TPB) {
        int g = s / C_SLOT;             // constant divisor -> magic mul
        int idx = s - g * C_SLOT;
        if (idx < cnt[g]) {
            uint4 rec = rbase[s];
            int local = (int)(rec.x & (NODES_PER_B - 1));
            atomicAdd(&accum[local * 3 + 0], __uint_as_float(rec.y)); // ds_add_f32
            atomicAdd(&accum[local * 3 + 1], __uint_as_float(rec.z));
            atomicAdd(&accum[local * 3 + 2], __uint_as_float(rec.w));
        }
    }
    __syncthreads();

    int obase = bucket * NODES_PER_B * 3;
    for (int i = t; i < NODES_PER_B * 3; i += TPB)
        if (obase + i < out_size) out[obase + i] = accum[i];
}

// ---------------- phase 3: apply rare overflow records ----------------
__global__ void __launch_bounds__(TPB)
p3_overflow(const uint4* __restrict__ ovf, const int* __restrict__ ovf_cnt,
            float* __restrict__ out) {
    int n = *ovf_cnt;
    if (n > OCAP) n = OCAP;
    int stride = gridDim.x * blockDim.x;
    for (int i = blockIdx.x * blockDim.x + threadIdx.x; i < n; i += stride) {
        uint4 rec = ovf[i];
        int node = (int)rec.x;
        unsafeAtomicAdd(&out[node * 3 + 0], __uint_as_float(rec.y));
        unsafeAtomicAdd(&out[node * 3 + 1], __uint_as_float(rec.z));
        unsafeAtomicAdd(&out[node * 3 + 2], __uint_as_float(rec.w));
    }
}

// ---------------- fallback: direct atomic scatter ----------------
__global__ void __launch_bounds__(TPB)
edge_force_scatter_direct(const float* __restrict__ disp,
                          const float* __restrict__ a,
                          const float* __restrict__ b,
                          const int* __restrict__ src,
                          const int* __restrict__ dst,
                          float* __restrict__ out,
                          int E) {
    int e = blockIdx.x * blockDim.x + threadIdx.x;
    if (e >= E) return;
    float dx = disp[3 * e + 0], dy = disp[3 * e + 1], dz = disp[3 * e + 2];
    float r2 = dx * dx + dy * dy + dz * dz;
    float coef = -2.0f * (a[e] - b[e] * __expf(-r2));
    float fx = coef * dx, fy = coef * dy, fz = coef * dz;
    int s = 3 * src[e], d = 3 * dst[e];
    unsafeAtomicAdd(&out[s + 0], fx);
    unsafeAtomicAdd(&out[s + 1], fy);
    unsafeAtomicAdd(&out[s + 2], fz);
    unsafeAtomicAdd(&out[d + 0], -fx);
    unsafeAtomicAdd(&out[d + 1], -fy);
    unsafeAtomicAdd(&out[d + 2], -fz);
}

extern "C" void kernel_launch(void* const* d_in, const int* in_sizes, int n_in,
                              void* d_out, int out_size, void* d_ws, size_t ws_size,
                              hipStream_t stream) {
    const float* disp = (const float*)d_in[0];   // [E,3]
    const float* a    = (const float*)d_in[1];   // [E]
    const float* b    = (const float*)d_in[2];   // [E]
    const int*   ei   = (const int*)d_in[3];     // [2,E]

    int E = in_sizes[1];
    int N = in_sizes[4];
    float* out = (float*)d_out;

    int NB = (N + NODES_PER_B - 1) / NODES_PER_B;
    int nblocks = (E + EPB - 1) / EPB;

    size_t rec_slots = (size_t)NB * nblocks * C_SLOT;
    size_t need = rec_slots * sizeof(uint4)
                + (size_t)OCAP * sizeof(uint4)
                + (size_t)NB * nblocks * sizeof(int)
                + 64;

    if (NB <= MAX_NB && nblocks <= MAX_BLOCKS && ws_size >= need) {
        uint4* records = (uint4*)d_ws;
        uint4* ovf     = records + rec_slots;
        int*   counts  = (int*)(ovf + OCAP);
        int*   ovf_cnt = counts + (size_t)NB * nblocks;

        hipMemsetAsync(ovf_cnt, 0, sizeof(int), stream);

        p1_force_bucket<<<nblocks, TPB, 0, stream>>>(
            disp, a, b, ei, ei + E, records, counts, ovf, ovf_cnt, E, NB, nblocks);
        p2_bucket_reduce<<<NB, TPB, 0, stream>>>(
            records, counts, out, nblocks, out_size);
        p3_overflow<<<64, TPB, 0, stream>>>(ovf, ovf_cnt, out);
    } else {
        hipMemsetAsync(d_out, 0, (size_t)out_size * sizeof(float), stream);
        int grid = (E + TPB - 1) / TPB;
        edge_force_scatter_direct<<<grid, TPB, 0, stream>>>(
            disp, a, b, ei, ei + E, out, E);
    }
}